// Round 1
// baseline (378.624 us; speedup 1.0000x reference)
//
#include <hip/hip_runtime.h>

#define B_DIM   512
#define IN_DIM  65536
#define OUT_DIM 16384
#define K_DIM   32

// ---------------------------------------------------------------------------
// Kernel 1: transpose x (B_DIM x IN_DIM) -> xT (IN_DIM x B_DIM)
// 64x64 tiles via LDS, float4 global loads/stores (fully coalesced).
// ---------------------------------------------------------------------------
#define TT 64
__global__ __launch_bounds__(256) void transpose_k(const float* __restrict__ x,
                                                   float* __restrict__ xT) {
    __shared__ float tile[TT][TT + 1];  // +1 pad: <=2-way bank aliasing (free)
    const int c0 = blockIdx.x * TT;  // column base in x (= row base in xT)
    const int r0 = blockIdx.y * TT;  // row base in x    (= col base in xT)
    const int t  = threadIdx.x;
    const int cq = (t & 15) * 4;     // 16 lanes x float4 = 64 cols
    const int r  = t >> 4;           // 16 rows per pass

    #pragma unroll
    for (int rr = 0; rr < TT; rr += 16) {
        float4 v = *(const float4*)(x + (size_t)(r0 + r + rr) * IN_DIM + c0 + cq);
        tile[cq + 0][r + rr] = v.x;
        tile[cq + 1][r + rr] = v.y;
        tile[cq + 2][r + rr] = v.z;
        tile[cq + 3][r + rr] = v.w;
    }
    __syncthreads();

    const int rq = (t & 15) * 4;     // b-quad in xT row
    const int c  = t >> 4;
    #pragma unroll
    for (int cc = 0; cc < TT; cc += 16) {
        float4 v;
        v.x = tile[c + cc][rq + 0];
        v.y = tile[c + cc][rq + 1];
        v.z = tile[c + cc][rq + 2];
        v.w = tile[c + cc][rq + 3];
        *(float4*)(xT + (size_t)(c0 + c + cc) * B_DIM + r0 + rq) = v;
    }
}

// ---------------------------------------------------------------------------
// Kernel 2: main. Block = 128 threads, owns O_TILE outputs x all 512 b's.
// Thread t holds b = 4t..4t+3 (float4). For each (o,k): idx/w are wave-uniform
// (scalar loads); the gather xT[idx][4t..4t+3] is a perfectly coalesced 1 KB
// per-wave load from a contiguous 2 KB row. Epilogue corner-turns through LDS
// so the (b,o)-layout out writes are o-contiguous float4.
// ---------------------------------------------------------------------------
#define O_TILE 16
#define LDS_STRIDE 520  // 520 % 32 == 8 -> conflict-free epilogue reads; 16B-aligned rows

__global__ __launch_bounds__(128) void sparse_main(const float* __restrict__ xT,
                                                   const int*   __restrict__ idxp,
                                                   const float* __restrict__ wp,
                                                   const float* __restrict__ biasp,
                                                   float*       __restrict__ out) {
    __shared__ float lds[O_TILE][LDS_STRIDE];
    const int o_base = blockIdx.x * O_TILE;
    const int t  = threadIdx.x;
    const int b4 = t * 4;

    float4 acc[O_TILE];
    #pragma unroll
    for (int o = 0; o < O_TILE; ++o) acc[o] = make_float4(0.f, 0.f, 0.f, 0.f);

    for (int k = 0; k < K_DIM; ++k) {
        #pragma unroll
        for (int o = 0; o < O_TILE; ++o) {
            const int   idx = idxp[(o_base + o) * K_DIM + k];  // uniform -> s_load
            const float w   = wp [(o_base + o) * K_DIM + k];   // uniform -> s_load
            const float4 v  = *(const float4*)(xT + (size_t)idx * B_DIM + b4);
            acc[o].x = fmaf(w, v.x, acc[o].x);
            acc[o].y = fmaf(w, v.y, acc[o].y);
            acc[o].z = fmaf(w, v.z, acc[o].z);
            acc[o].w = fmaf(w, v.w, acc[o].w);
        }
    }

    // bias + stage to LDS (b-major within each o row)
    #pragma unroll
    for (int o = 0; o < O_TILE; ++o) {
        const float bv = biasp[o_base + o];
        acc[o].x += bv; acc[o].y += bv; acc[o].z += bv; acc[o].w += bv;
        *(float4*)(&lds[o][b4]) = acc[o];
    }
    __syncthreads();

    // corner-turn write: out[b][o_base+o], o-contiguous float4, full-line writes
    #pragma unroll
    for (int p = 0; p < 16; ++p) {
        const int q = p * 512 + t * 4;      // linear over 512 b x 16 o
        const int b = q >> 4;
        const int o = q & 15;               // multiple of 4
        float4 v;
        v.x = lds[o + 0][b];
        v.y = lds[o + 1][b];
        v.z = lds[o + 2][b];
        v.w = lds[o + 3][b];
        *(float4*)(out + (size_t)b * OUT_DIM + o_base + o) = v;
    }
}

// ---------------------------------------------------------------------------
// Fallback (only if workspace can't hold xT): direct gather, correct but slow.
// ---------------------------------------------------------------------------
__global__ void sparse_fallback(const float* __restrict__ x,
                                const int*   __restrict__ idxp,
                                const float* __restrict__ wp,
                                const float* __restrict__ biasp,
                                float*       __restrict__ out) {
    const int i = blockIdx.x * blockDim.x + threadIdx.x;
    if (i >= B_DIM * OUT_DIM) return;
    const int b = i / OUT_DIM;
    const int o = i % OUT_DIM;
    float a = biasp[o];
    for (int k = 0; k < K_DIM; ++k) {
        const int idx = idxp[o * K_DIM + k];
        a = fmaf(wp[o * K_DIM + k], x[(size_t)b * IN_DIM + idx], a);
    }
    out[i] = a;
}

extern "C" void kernel_launch(void* const* d_in, const int* in_sizes, int n_in,
                              void* d_out, int out_size, void* d_ws, size_t ws_size,
                              hipStream_t stream) {
    const float* x       = (const float*)d_in[0];
    const int*   indices = (const int*)  d_in[1];
    const float* weight  = (const float*)d_in[2];
    const float* bias    = (const float*)d_in[3];
    float*       out     = (float*)d_out;

    const size_t need = (size_t)IN_DIM * B_DIM * sizeof(float);  // 128 MiB
    if (ws_size >= need) {
        float* xT = (float*)d_ws;
        dim3 tgrid(IN_DIM / TT, B_DIM / TT);  // (1024, 8)
        transpose_k<<<tgrid, 256, 0, stream>>>(x, xT);
        sparse_main<<<OUT_DIM / O_TILE, 128, 0, stream>>>(xT, indices, weight, bias, out);
    } else {
        const int n = B_DIM * OUT_DIM;
        sparse_fallback<<<(n + 255) / 256, 256, 0, stream>>>(x, indices, weight, bias, out);
    }
}

// Round 2
// 349.313 us; speedup vs baseline: 1.0839x; 1.0839x over previous
//
#include <hip/hip_runtime.h>

#define B_DIM   512
#define IN_DIM  65536
#define OUT_DIM 16384
#define K_DIM   32

static __device__ __forceinline__ unsigned short f2bf(float f) {
    unsigned u = __builtin_bit_cast(unsigned, f);
    unsigned r = (u + 0x7FFFu + ((u >> 16) & 1u)) >> 16;   // round-to-nearest-even
    return (unsigned short)r;
}
static __device__ __forceinline__ float bf2f(unsigned short s) {
    return __builtin_bit_cast(float, ((unsigned)s) << 16);
}

// ---------------------------------------------------------------------------
// Kernel 1: fused transpose + fp32->bf16 downconvert.
// x (B_DIM x IN_DIM, fp32) -> xT (IN_DIM x B_DIM, bf16)
// Tile: 128 b-rows x 64 in-cols. Reads: 256 B chunks/row. Writes: 256 B
// chunks/xT-row (32 lanes x ushort4). LDS stride 65 floats: store phase
// 2-way (free), load phase 4-way scalar (1.58x, negligible here).
// ---------------------------------------------------------------------------
#define TB 128   // b rows per tile
#define TC 64    // in cols per tile
#define TS 65    // LDS row stride (floats), odd => banks spread

__global__ __launch_bounds__(256) void transpose_bf16_k(const float* __restrict__ x,
                                                        unsigned short* __restrict__ xT) {
    __shared__ float tile[TB][TS];
    const int c0 = blockIdx.x * TC;
    const int b0 = blockIdx.y * TB;
    const int t  = threadIdx.x;

    // read phase: 16 b-rows per pass, 8 passes
    const int col4 = (t & 15) * 4;
    const int br   = t >> 4;
    #pragma unroll
    for (int rr = 0; rr < TB; rr += 16) {
        float4 v = *(const float4*)(x + (size_t)(b0 + br + rr) * IN_DIM + c0 + col4);
        tile[br + rr][col4 + 0] = v.x;
        tile[br + rr][col4 + 1] = v.y;
        tile[br + rr][col4 + 2] = v.z;
        tile[br + rr][col4 + 3] = v.w;
    }
    __syncthreads();

    // write phase: lanes span b (transposed), pack 4 b's -> ushort4 (8 B)
    const int b4 = (t & 31) * 4;
    const int cw = t >> 5;              // 0..7
    #pragma unroll
    for (int cc = 0; cc < TC; cc += 8) {
        const int c = cc + cw;
        ushort4 p;
        p.x = f2bf(tile[b4 + 0][c]);
        p.y = f2bf(tile[b4 + 1][c]);
        p.z = f2bf(tile[b4 + 2][c]);
        p.w = f2bf(tile[b4 + 3][c]);
        *(ushort4*)(xT + (size_t)(c0 + c) * B_DIM + b0 + b4) = p;
    }
}

// ---------------------------------------------------------------------------
// Kernel 2: main. Block = 128 threads owns O_TILE=8 outputs x all 512 b's.
// Thread t holds b = 4t..4t+3. idx/w are block-uniform -> scalar loads.
// Gather: ushort4 (8 B) from a contiguous 1 KB bf16 row -> per-wave 512 B
// fully-coalesced; xT (64 MiB) is L3-resident so reuse (~8x per row) hits L3.
// Epilogue corner-turns through LDS so out writes are 1 KB contiguous/wave.
// ---------------------------------------------------------------------------
#define O_TILE 8
#define SE 520   // epilogue LDS stride: %32==8 -> 2-way reads; 16B-aligned rows

__global__ __launch_bounds__(128) void sparse_main(const unsigned short* __restrict__ xT,
                                                   const int*   __restrict__ idxp,
                                                   const float* __restrict__ wp,
                                                   const float* __restrict__ biasp,
                                                   float*       __restrict__ out) {
    __shared__ float lds[O_TILE][SE];
    const int o_base = blockIdx.x * O_TILE;
    const int t  = threadIdx.x;
    const int b4 = t * 4;

    float4 acc[O_TILE];
    #pragma unroll
    for (int o = 0; o < O_TILE; ++o) acc[o] = make_float4(0.f, 0.f, 0.f, 0.f);

    for (int k = 0; k < K_DIM; ++k) {
        #pragma unroll
        for (int o = 0; o < O_TILE; ++o) {
            const int   idx = idxp[(o_base + o) * K_DIM + k];   // uniform -> s_load
            const float w   = wp [(o_base + o) * K_DIM + k];    // uniform -> s_load
            const ushort4 v = *(const ushort4*)(xT + (size_t)idx * B_DIM + b4);
            acc[o].x = fmaf(w, bf2f(v.x), acc[o].x);
            acc[o].y = fmaf(w, bf2f(v.y), acc[o].y);
            acc[o].z = fmaf(w, bf2f(v.z), acc[o].z);
            acc[o].w = fmaf(w, bf2f(v.w), acc[o].w);
        }
    }

    #pragma unroll
    for (int o = 0; o < O_TILE; ++o) {
        const float bv = biasp[o_base + o];
        acc[o].x += bv; acc[o].y += bv; acc[o].z += bv; acc[o].w += bv;
        *(float4*)(&lds[o][b4]) = acc[o];
    }
    __syncthreads();

    // corner-turn write: 512 b x 8 o = 4096 floats, 8 passes of 512
    #pragma unroll
    for (int p = 0; p < 8; ++p) {
        const int q = p * 512 + t * 4;
        const int b = q >> 3;
        const int o = q & 7;            // 0 or 4
        float4 v;
        v.x = lds[o + 0][b];
        v.y = lds[o + 1][b];
        v.z = lds[o + 2][b];
        v.w = lds[o + 3][b];
        *(float4*)(out + (size_t)b * OUT_DIM + o_base + o) = v;
    }
}

// ---------------------------------------------------------------------------
// Fallback (workspace too small): direct gather, correct but slow.
// ---------------------------------------------------------------------------
__global__ void sparse_fallback(const float* __restrict__ x,
                                const int*   __restrict__ idxp,
                                const float* __restrict__ wp,
                                const float* __restrict__ biasp,
                                float*       __restrict__ out) {
    const int i = blockIdx.x * blockDim.x + threadIdx.x;
    if (i >= B_DIM * OUT_DIM) return;
    const int b = i / OUT_DIM;
    const int o = i % OUT_DIM;
    float a = biasp[o];
    for (int k = 0; k < K_DIM; ++k) {
        const int idx = idxp[o * K_DIM + k];
        a = fmaf(wp[o * K_DIM + k], x[(size_t)b * IN_DIM + idx], a);
    }
    out[i] = a;
}

extern "C" void kernel_launch(void* const* d_in, const int* in_sizes, int n_in,
                              void* d_out, int out_size, void* d_ws, size_t ws_size,
                              hipStream_t stream) {
    const float* x       = (const float*)d_in[0];
    const int*   indices = (const int*)  d_in[1];
    const float* weight  = (const float*)d_in[2];
    const float* bias    = (const float*)d_in[3];
    float*       out     = (float*)d_out;

    const size_t need = (size_t)IN_DIM * B_DIM * sizeof(unsigned short);  // 64 MiB
    if (ws_size >= need) {
        unsigned short* xT = (unsigned short*)d_ws;
        dim3 tgrid(IN_DIM / TC, B_DIM / TB);   // (1024, 4)
        transpose_bf16_k<<<tgrid, 256, 0, stream>>>(x, xT);
        sparse_main<<<OUT_DIM / O_TILE, 128, 0, stream>>>(xT, indices, weight, bias, out);
    } else {
        const int n = B_DIM * OUT_DIM;
        sparse_fallback<<<(n + 255) / 256, 256, 0, stream>>>(x, indices, weight, bias, out);
    }
}

// Round 3
// 325.496 us; speedup vs baseline: 1.1632x; 1.0732x over previous
//
#include <hip/hip_runtime.h>

#define B_DIM   512
#define IN_DIM  65536
#define OUT_DIM 16384
#define K_DIM   32

static __device__ __forceinline__ unsigned short f2bf(float f) {
    unsigned u = __builtin_bit_cast(unsigned, f);
    unsigned r = (u + 0x7FFFu + ((u >> 16) & 1u)) >> 16;   // round-to-nearest-even
    return (unsigned short)r;
}

// ---------------------------------------------------------------------------
// Kernel 1: transpose + fp32->bf16, NO LDS.
// Block = 256 threads, tile = 16 in-cols x all 512 b.
// Read: each thread grabs the full 64 B line x[b][c0..c0+16) (4x float4; the
// 4 loads hit the same line -> 1 miss + 3 L1 hits). Write: xT[c][b] ushort
// stores, consecutive lanes = consecutive b -> 128 B per wave-instr,
// contiguous 1 KiB rows -> L2 write-combines to full lines.
// ---------------------------------------------------------------------------
static __device__ __forceinline__ float fcomp(float4 v, int c) {
    switch (c & 3) { case 0: return v.x; case 1: return v.y; case 2: return v.z; default: return v.w; }
}

__global__ __launch_bounds__(256) void transpose_bf16_k(const float* __restrict__ x,
                                                        unsigned short* __restrict__ xT) {
    const int c0 = blockIdx.x * 16;
    const int t  = threadIdx.x;
    #pragma unroll
    for (int h = 0; h < 2; ++h) {
        const int b = h * 256 + t;
        const float4* p = (const float4*)(x + (size_t)b * IN_DIM + c0);
        float4 v0 = p[0], v1 = p[1], v2 = p[2], v3 = p[3];
        #pragma unroll
        for (int c = 0; c < 16; ++c) {
            const float4 vv = (c < 4) ? v0 : (c < 8) ? v1 : (c < 12) ? v2 : v3;
            xT[(size_t)(c0 + c) * B_DIM + b] = f2bf(fcomp(vv, c));
        }
    }
}

// ---------------------------------------------------------------------------
// Kernel 2: main. Block = 128 threads (2 waves), owns 8 outputs x all 512 b.
// Each wave preloads the block's whole idx/w tile (8 o x 32 k) as one
// int4/float4 per lane, then broadcasts each (o,k) scalar via readlane ->
// no scalar-memory chain in the hot loop. o x k fully unrolled: 256
// independent uniform-row gathers (8 B/lane, 512 B/wave) -> deep MLP.
// Epilogue corner-turns through LDS for o-contiguous float4 out writes.
// ---------------------------------------------------------------------------
#define SE 520   // epilogue LDS stride

static __device__ __forceinline__ int icomp(int4 v, int c) {
    switch (c & 3) { case 0: return v.x; case 1: return v.y; case 2: return v.z; default: return v.w; }
}

__global__ __launch_bounds__(128, 4) void sparse_main(const unsigned short* __restrict__ xT,
                                                      const int*   __restrict__ idxp,
                                                      const float* __restrict__ wp,
                                                      const float* __restrict__ biasp,
                                                      float*       __restrict__ out) {
    __shared__ float lds[8][SE];
    const int o_blk = blockIdx.x * 8;
    const int t    = threadIdx.x;
    const int lane = t & 63;
    const int b4   = t * 4;          // this thread's 4 b's

    // whole idx/w tile for the block's 8 o's: 256 ints = 64 lanes x int4
    const int4   iv = ((const int4*)  (idxp + o_blk * K_DIM))[lane];
    const float4 wv = ((const float4*)(wp   + o_blk * K_DIM))[lane];

    float4 acc[8];
    #pragma unroll
    for (int o = 0; o < 8; ++o) acc[o] = make_float4(0.f, 0.f, 0.f, 0.f);

    #pragma unroll
    for (int o = 0; o < 8; ++o) {
        #pragma unroll
        for (int k = 0; k < K_DIM; ++k) {
            const int flat = o * K_DIM + k;          // element (o,k) lives in
            const int sl   = flat >> 2;              // lane sl, component flat&3
            const int   sidx = __builtin_amdgcn_readlane(icomp(iv, flat), sl);
            const float sw   = __int_as_float(
                __builtin_amdgcn_readlane(__float_as_int(fcomp(wv, flat)), sl));
            const uint2 u = *(const uint2*)(xT + ((size_t)sidx << 9) + b4);
            acc[o].x = fmaf(sw, __int_as_float(u.x << 16),          acc[o].x);
            acc[o].y = fmaf(sw, __int_as_float(u.x & 0xFFFF0000u),  acc[o].y);
            acc[o].z = fmaf(sw, __int_as_float(u.y << 16),          acc[o].z);
            acc[o].w = fmaf(sw, __int_as_float(u.y & 0xFFFF0000u),  acc[o].w);
        }
    }

    #pragma unroll
    for (int o = 0; o < 8; ++o) {
        const float bv = biasp[o_blk + o];
        acc[o].x += bv; acc[o].y += bv; acc[o].z += bv; acc[o].w += bv;
        *(float4*)(&lds[o][b4]) = acc[o];
    }
    __syncthreads();

    // corner-turn write: 512 b x 8 o = 4096 floats, 8 passes of 512
    #pragma unroll
    for (int p = 0; p < 8; ++p) {
        const int q = p * 512 + t * 4;
        const int b = q >> 3;
        const int o = q & 7;            // 0 or 4
        float4 v;
        v.x = lds[o + 0][b];
        v.y = lds[o + 1][b];
        v.z = lds[o + 2][b];
        v.w = lds[o + 3][b];
        *(float4*)(out + (size_t)b * OUT_DIM + o_blk + o) = v;
    }
}

// ---------------------------------------------------------------------------
// Fallback (workspace too small): direct gather, correct but slow.
// ---------------------------------------------------------------------------
__global__ void sparse_fallback(const float* __restrict__ x,
                                const int*   __restrict__ idxp,
                                const float* __restrict__ wp,
                                const float* __restrict__ biasp,
                                float*       __restrict__ out) {
    const int i = blockIdx.x * blockDim.x + threadIdx.x;
    if (i >= B_DIM * OUT_DIM) return;
    const int b = i / OUT_DIM;
    const int o = i % OUT_DIM;
    float a = biasp[o];
    for (int k = 0; k < K_DIM; ++k) {
        const int idx = idxp[o * K_DIM + k];
        a = fmaf(wp[o * K_DIM + k], x[(size_t)b * IN_DIM + idx], a);
    }
    out[i] = a;
}

extern "C" void kernel_launch(void* const* d_in, const int* in_sizes, int n_in,
                              void* d_out, int out_size, void* d_ws, size_t ws_size,
                              hipStream_t stream) {
    const float* x       = (const float*)d_in[0];
    const int*   indices = (const int*)  d_in[1];
    const float* weight  = (const float*)d_in[2];
    const float* bias    = (const float*)d_in[3];
    float*       out     = (float*)d_out;

    const size_t need = (size_t)IN_DIM * B_DIM * sizeof(unsigned short);  // 64 MiB
    if (ws_size >= need) {
        unsigned short* xT = (unsigned short*)d_ws;
        transpose_bf16_k<<<IN_DIM / 16, 256, 0, stream>>>(x, xT);
        sparse_main<<<OUT_DIM / 8, 128, 0, stream>>>(xT, indices, weight, bias, out);
    } else {
        const int n = B_DIM * OUT_DIM;
        sparse_fallback<<<(n + 255) / 256, 256, 0, stream>>>(x, indices, weight, bias, out);
    }
}